// Round 11
// baseline (367.945 us; speedup 1.0000x reference)
//
#include <hip/hip_runtime.h>
#include <math.h>

constexpr int EE = 128;    // embedding dim
constexpr int NS = 1024;   // spatial S
constexpr int NB = 32;     // batch
constexpr size_t BSE = (size_t)NB * NS * EE;  // 4194304 elems per (b,s,e) array

typedef __attribute__((ext_vector_type(4))) float f32x4;
typedef __attribute__((ext_vector_type(8))) short s16x8;
typedef __attribute__((ext_vector_type(4))) short s16x4;
typedef __attribute__((ext_vector_type(8))) __bf16 bf16v8;

__device__ __forceinline__ f32x4 mfma16(s16x8 a, s16x8 b, f32x4 c) {
  return __builtin_amdgcn_mfma_f32_16x16x32_bf16(
      __builtin_bit_cast(bf16v8, a), __builtin_bit_cast(bf16v8, b), c, 0, 0, 0);
}

__device__ __forceinline__ unsigned short f2bf(float f) {
  unsigned u = __builtin_bit_cast(unsigned, f);
  u += 0x7FFFu + ((u >> 16) & 1u);
  return (unsigned short)(u >> 16);
}
__device__ __forceinline__ float bf2f(unsigned short h) {
  unsigned u = ((unsigned)h) << 16;
  return __builtin_bit_cast(float, u);
}

// LDS XOR swizzles (involutions). 256B-row tiles: XOR 16B-slot bits 4-6 with row&7.
// 128B-row tiles (K-half staging): XOR bits 4-6 with bits 7-9.
__device__ __forceinline__ int swz(int b)  { return b ^ (((b >> 8) & 7) << 4); }
__device__ __forceinline__ int swz7(int b) { return b ^ (((b >> 7) & 7) << 4); }

__device__ __forceinline__ void gl_lds16(const void* gptr, void* lptr) {
  auto g = (const __attribute__((address_space(1))) unsigned int*)gptr;
  auto l = (__attribute__((address_space(3))) unsigned int*)lptr;
  __builtin_amdgcn_global_load_lds(g, l, 16, 0, 0);
}

// stage one contiguous 32KB global tile (256B rows) with source-side swz().
__device__ __forceinline__ void stage32k(const char* gsrc, char* ldst, int wv, int lane) {
#pragma unroll
  for (int c = 0; c < 8; ++c) {
    int uoff = c*4096 + wv*1024;              // wave-uniform LDS dest
    gl_lds16(gsrc + swz(uoff + lane*16), ldst + uoff);
  }
}

// stage a 16KB K-half (128B LDS rows) of a 256B-row global tile; swz7 on source.
__device__ __forceinline__ void stage_half(const char* tile, char* ldst, int kh, int wv, int lane) {
#pragma unroll
  for (int c = 0; c < 4; ++c) {
    int uoff = c*4096 + wv*1024;
    int sa = swz7(uoff + lane*16);
    gl_lds16(tile + (sa >> 7)*256 + kh*128 + (sa & 127), ldst + uoff);
  }
}

// ---------------- workspace layout (bytes) ----------------
constexpr size_t EMB_OFF   = 0;                                   // 12 bf16 arrays [p][side][b*S+s][e]
constexpr size_t UNP_OFF   = EMB_OFF + 12ull * BSE * 2;           // f32 [3][B][S]
constexpr size_t RB_OFF    = UNP_OFF + 3ull * NB * NS * 4;        // bf16 [6][S][S]
constexpr size_t CX_OFF    = RB_OFF + 6ull * NS * NS * 2;         // f32 [6][S]
constexpr size_t POTX_OFF  = CX_OFF + 6ull * NS * 4;              // f32 [6][B][S]
constexpr size_t PYP_OFF   = POTX_OFF + 6ull * NB * NS * 4;       // f32 [3][B][8][S] potY partials
constexpr size_t CY_OFF    = PYP_OFF + 3ull * NB * 8 * NS * 4;    // f32 [6][S]
constexpr size_t CXP_OFF   = CY_OFF + 6ull * NS * 4;              // f32 [6][8][S] cX partials
constexpr size_t CYP_OFF   = CXP_OFF + 6ull * 8 * NS * 4;         // f32 [3][8][S] cY partials
constexpr size_t WBF_OFF   = CYP_OFF + 3ull * 8 * NS * 4;         // bf16 [15][128*128] weights
constexpr size_t WTS_OFF   = WBF_OFF + 15ull * EE * EE * 2;       // f32 [3][B][S] softmax weights
constexpr size_t PART_OFF  = WTS_OFF + 3ull * NB * NS * 4;        // f32 [3][B][8][128] bmm partials

// ================= wprep: f32 -> bf16 weight matrices (once) =================
__global__ void wprep_kernel(
    const float* __restrict__ un_w1, const float* __restrict__ sp_wx,
    const float* __restrict__ sp_wy, const float* __restrict__ pw_wx,
    const float* __restrict__ pw_wy, unsigned short* __restrict__ wbf)
{
  const int i = (blockIdx.x * 256 + threadIdx.x) * 4;   // elem index, 245760 total
  const int m15 = i >> 14, off = i & 16383;
  const float* src;
  if (m15 < 3)       src = un_w1 + (size_t)m15 * 16384;
  else if (m15 < 6)  src = sp_wx + (size_t)(m15 - 3) * 16384;
  else if (m15 < 9)  src = sp_wy + (size_t)(m15 - 6) * 16384;
  else if (m15 < 12) src = pw_wx + (size_t)(m15 - 9) * 16384;
  else               src = pw_wy + (size_t)(m15 - 12) * 16384;
  float4 v = *(const float4*)(src + off);
  s16x4 h;
  h.x = (short)f2bf(v.x); h.y = (short)f2bf(v.y);
  h.z = (short)f2bf(v.z); h.w = (short)f2bf(v.w);
  *(s16x4*)(wbf + i) = h;
}

// ================= embed kernel (fused; bf16 weights staged async) ===========
__global__ __launch_bounds__(256, 3) void embed_kernel(
    const float* __restrict__ utils, const unsigned short* __restrict__ wbf,
    const float* __restrict__ un_b1, const float* __restrict__ un_w2,
    const float* __restrict__ un_b2,
    const float* __restrict__ sp_bx, const float* __restrict__ sp_by,
    const float* __restrict__ pw_bx, const float* __restrict__ pw_by,
    unsigned short* __restrict__ emb, float* __restrict__ unp)
{
  const int u  = blockIdx.x >> 9;
  const int pt = blockIdx.x & 511;

  __shared__ short lA[64*128];
  __shared__ short lB[128*128];
  __shared__ float redbuf[64];

  const int t = threadIdx.x;
  {
    const char* src = (const char*)(utils + (size_t)u*BSE + (size_t)pt*64*EE);
#pragma unroll
    for (int c = 0; c < 8; ++c) {
      int off = c*4096 + t*16;
      float4 v = *(const float4*)(src + off);
      s16x4 h;
      h.x = (short)f2bf(v.x); h.y = (short)f2bf(v.y);
      h.z = (short)f2bf(v.z); h.w = (short)f2bf(v.w);
      *(s16x4*)((char*)lA + swz(off >> 1)) = h;
    }
  }

  const int lane = t & 63, wv = t >> 6;
  const int wrE = wv & 1, wcE = wv >> 1;
  const int cL = lane & 15, r4 = (lane >> 4) * 4, k8 = (lane >> 4) * 8;

  for (int m = 0; m < 5; ++m) {
    int wid; const float* bias;
    unsigned short* dst = nullptr;
    int mode;
    if (m == 0)      { wid = u;     bias = un_b1 + u*EE; mode = 0; }
    else if (m == 1) { wid = 3 + u; bias = sp_bx + u*EE; dst = emb + (size_t)(2*u)*BSE;   mode = 1; }
    else if (m == 2) { wid = 6 + u; bias = sp_by + u*EE; dst = emb + (size_t)(2*u+1)*BSE; mode = 1; }
    else {
      int q, side;
      if (u == 0)      { q = (m == 3) ? 0 : 1; side = 0; }
      else if (u == 1) { if (m == 3) { q = 0; side = 1; } else { q = 2; side = 0; } }
      else             { q = (m == 3) ? 1 : 2; side = 1; }
      wid  = (side == 0 ? 9 : 12) + q;
      bias = (side == 0 ? pw_bx : pw_by) + q*EE;
      dst  = emb + (size_t)(2*(3+q)+side)*BSE;
      mode = 1;
    }

    __syncthreads();   // lA writes done (m=0) / prev iter's lB reads done
    stage32k((const char*)wbf + (size_t)wid * 32768, (char*)lB, wv, lane);
    __syncthreads();   // drain: lB ready

    f32x4 acc[2][4];
#pragma unroll
    for (int i = 0; i < 2; ++i)
#pragma unroll
      for (int j = 0; j < 4; ++j) acc[i][j] = f32x4{0.f, 0.f, 0.f, 0.f};

#pragma unroll
    for (int kk = 0; kk < 4; ++kk) {
      s16x8 av[2], bv[4];
#pragma unroll
      for (int i = 0; i < 2; ++i) {
        int row = wrE*32 + i*16 + cL;
        av[i] = *(const s16x8*)((const char*)lA + swz(row*256 + kk*64 + k8*2));
      }
#pragma unroll
      for (int j = 0; j < 4; ++j) {
        int row = wcE*64 + j*16 + cL;
        bv[j] = *(const s16x8*)((const char*)lB + swz(row*256 + kk*64 + k8*2));
      }
#pragma unroll
      for (int i = 0; i < 2; ++i)
#pragma unroll
        for (int j = 0; j < 4; ++j)
          acc[i][j] = mfma16(av[i], bv[j], acc[i][j]);
    }

    if (mode == 0) {
      const float* w2 = un_w2 + u*EE;
      float s[2][4];
#pragma unroll
      for (int i = 0; i < 2; ++i)
#pragma unroll
        for (int r = 0; r < 4; ++r) s[i][r] = 0.f;
#pragma unroll
      for (int i = 0; i < 2; ++i) {
#pragma unroll
        for (int j = 0; j < 4; ++j) {
          int o = wcE*64 + j*16 + cL;
          float bv2 = bias[o], w2v = w2[o];
#pragma unroll
          for (int r = 0; r < 4; ++r) {
            float v = acc[i][j][r] + bv2;
            v = v > 0.f ? v : 0.f;
            s[i][r] += v * w2v;
          }
        }
      }
#pragma unroll
      for (int msk = 1; msk < 16; msk <<= 1)
#pragma unroll
        for (int i = 0; i < 2; ++i)
#pragma unroll
          for (int r = 0; r < 4; ++r)
            s[i][r] += __shfl_xor(s[i][r], msk, 64);
      if (t < 64) redbuf[t] = 0.f;
      __syncthreads();
      if (cL == 0) {
#pragma unroll
        for (int i = 0; i < 2; ++i)
#pragma unroll
          for (int r = 0; r < 4; ++r)
            atomicAdd(&redbuf[wrE*32 + i*16 + r4 + r], s[i][r]);
      }
      __syncthreads();
      if (t < 64) unp[(size_t)u*NB*NS + (size_t)pt*64 + t] = redbuf[t] + un_b2[u];
    } else {
      float nrm[2][4];
#pragma unroll
      for (int i = 0; i < 2; ++i)
#pragma unroll
        for (int r = 0; r < 4; ++r) nrm[i][r] = 0.f;
#pragma unroll
      for (int i = 0; i < 2; ++i) {
#pragma unroll
        for (int j = 0; j < 4; ++j) {
          int o = wcE*64 + j*16 + cL;
          float bv2 = bias[o];
#pragma unroll
          for (int r = 0; r < 4; ++r) {
            acc[i][j][r] += bv2;
            nrm[i][r] += acc[i][j][r] * acc[i][j][r];
          }
        }
      }
#pragma unroll
      for (int msk = 1; msk < 16; msk <<= 1)
#pragma unroll
        for (int i = 0; i < 2; ++i)
#pragma unroll
          for (int r = 0; r < 4; ++r)
            nrm[i][r] += __shfl_xor(nrm[i][r], msk, 64);
      if (t < 64) redbuf[t] = 0.f;
      __syncthreads();
      if (cL == 0) {
#pragma unroll
        for (int i = 0; i < 2; ++i)
#pragma unroll
          for (int r = 0; r < 4; ++r)
            atomicAdd(&redbuf[wrE*32 + i*16 + r4 + r], nrm[i][r]);
      }
      __syncthreads();
#pragma unroll
      for (int i = 0; i < 2; ++i) {
#pragma unroll
        for (int r = 0; r < 4; ++r) {
          float n = redbuf[wrE*32 + i*16 + r4 + r];
          float sc = 1.f / fmaxf(sqrtf(n), 1e-12f);
          size_t pbase = ((size_t)pt*64 + wrE*32 + i*16 + r4 + r) * EE;
#pragma unroll
          for (int j = 0; j < 4; ++j) {
            int o = wcE*64 + j*16 + cL;
            dst[pbase + o] = f2bf(acc[i][j][r] * sc);
          }
        }
      }
    }
  }
}

// ================= pass 1: batch stats of S, fused BN-stats epilogue =========
// Counted-vmcnt pipeline (T4): issue stage(s+1), wait vmcnt(8) [= stage(s)
// landed, stage(s+1) stays in flight], raw barrier, MFMA, raw barrier.
__global__ __launch_bounds__(256, 2) void pass1_kernel(
    const unsigned short* __restrict__ emb,
    const float* __restrict__ sp_g, const float* __restrict__ sp_b,
    const float* __restrict__ sp_mxw,
    const float* __restrict__ pw_g, const float* __restrict__ pw_b,
    const float* __restrict__ pw_mxw, const float* __restrict__ pw_myw,
    unsigned short* __restrict__ Rb, float* __restrict__ cXpart,
    float* __restrict__ cYpart)
{
  const int bid = blockIdx.x;
  const int p = bid >> 6, xt = (bid >> 3) & 7, yt = bid & 7;
  const char* Xe = (const char*)(emb + (size_t)(2*p)*BSE + (size_t)xt*128*EE);
  const char* Ye = (const char*)(emb + (size_t)(2*p+1)*BSE + (size_t)yt*128*EE);
  __shared__ char lds[65536];   // buf[2] x (A-half 16K | B-half 16K)
  __shared__ float cxbuf[128];
  __shared__ float cybuf[128];
  const int t = threadIdx.x, lane = t & 63, wv = t >> 6;
  const int wr = wv >> 1, wc = wv & 1, cL = lane & 15, r4 = (lane >> 4) * 4;
  const int q16 = (lane >> 4) * 16;   // byte offset of K-subslice in 128B row

  f32x4 sS[4][4], sQ[4][4], acc[4][4];
#pragma unroll
  for (int i = 0; i < 4; ++i)
#pragma unroll
    for (int j = 0; j < 4; ++j) { sS[i][j] = f32x4{0.f,0.f,0.f,0.f}; sQ[i][j] = f32x4{0.f,0.f,0.f,0.f}; }

  stage_half(Xe, lds, 0, wv, lane);
  stage_half(Ye, lds + 16384, 0, wv, lane);
  if (t < 128) { cxbuf[t] = 0.f; cybuf[t] = 0.f; }

  for (int s = 0; s < 2*NB; ++s) {
    const int cur = s & 1;
    const char* buf = lds + cur * 32768;
    if (s + 1 < 2*NB) {
      const int b1 = (s + 1) >> 1, kh1 = (s + 1) & 1;
      char* nb = lds + (cur ^ 1) * 32768;
      stage_half(Xe + (size_t)b1*NS*EE*2, nb, kh1, wv, lane);
      stage_half(Ye + (size_t)b1*NS*EE*2, nb + 16384, kh1, wv, lane);
      asm volatile("s_waitcnt vmcnt(8)" ::: "memory");   // stage(s) landed
    } else {
      asm volatile("s_waitcnt vmcnt(0)" ::: "memory");
    }
    __builtin_amdgcn_sched_barrier(0);
    __builtin_amdgcn_s_barrier();                        // all waves: stage(s) visible
    __builtin_amdgcn_sched_barrier(0);

    if ((s & 1) == 0) {
#pragma unroll
      for (int i = 0; i < 4; ++i)
#pragma unroll
        for (int j = 0; j < 4; ++j) acc[i][j] = f32x4{0.f,0.f,0.f,0.f};
    }
#pragma unroll
    for (int kk2 = 0; kk2 < 2; ++kk2) {
      s16x8 av[4], bv[4];
#pragma unroll
      for (int i = 0; i < 4; ++i) {
        int row = wr*64 + i*16 + cL;
        av[i] = *(const s16x8*)(buf + swz7(row*128 + kk2*64 + q16));
      }
#pragma unroll
      for (int j = 0; j < 4; ++j) {
        int row = wc*64 + j*16 + cL;
        bv[j] = *(const s16x8*)(buf + 16384 + swz7(row*128 + kk2*64 + q16));
      }
#pragma unroll
      for (int i = 0; i < 4; ++i)
#pragma unroll
        for (int j = 0; j < 4; ++j)
          acc[i][j] = mfma16(av[i], bv[j], acc[i][j]);
    }
    if (s & 1) {
#pragma unroll
      for (int i = 0; i < 4; ++i)
#pragma unroll
        for (int j = 0; j < 4; ++j) {
          sS[i][j] += acc[i][j];
          sQ[i][j] += acc[i][j] * acc[i][j];
        }
    }
    __builtin_amdgcn_sched_barrier(0);
    __builtin_amdgcn_s_barrier();                        // reads of buf[cur] done
    __builtin_amdgcn_sched_barrier(0);
  }

  // ---- fused BN-stats epilogue ----
  const float* gp  = (p < 3) ? (sp_g + (size_t)p*NS*NS) : (pw_g + (size_t)(p-3)*NS*NS);
  const float* bbp = (p < 3) ? (sp_b + (size_t)p*NS*NS) : (pw_b + (size_t)(p-3)*NS*NS);
  const float* mxw = (p < 3) ? (sp_mxw + p*NS) : (pw_mxw + (p-3)*NS);
  const float* myw = (p < 3) ? nullptr : (pw_myw + (p-3)*NS);
  unsigned short* Rp = Rb + (size_t)p*NS*NS;
  const float inv = 1.f / 32.f;

  float mxl[4];
#pragma unroll
  for (int j = 0; j < 4; ++j) mxl[j] = mxw[yt*128 + wc*64 + j*16 + cL];
  float mywr[4][4];
  if (myw) {
#pragma unroll
    for (int i = 0; i < 4; ++i)
#pragma unroll
      for (int r = 0; r < 4; ++r)
        mywr[i][r] = myw[xt*128 + wr*64 + i*16 + r4 + r];
  }

  float py[4] = {0.f, 0.f, 0.f, 0.f};
#pragma unroll
  for (int i = 0; i < 4; ++i) {
#pragma unroll
    for (int r = 0; r < 4; ++r) {
      const size_t rowoff = (size_t)(xt*128 + wr*64 + i*16 + r4 + r)*NS + yt*128;
      float cxv = 0.f;
#pragma unroll
      for (int j = 0; j < 4; ++j) {
        int c = wc*64 + j*16 + cL;
        float mean = sS[i][j][r] * inv;
        float var  = sQ[i][j][r] * inv - mean * mean;
        float rstd = rsqrtf(var + 1e-5f);
        unsigned short rh = f2bf(gp[rowoff + c] * rstd);
        Rp[rowoff + c] = rh;
        float ct = bbp[rowoff + c] - bf2f(rh) * mean;
        cxv += mxl[j] * ct;
        if (myw) py[j] += mywr[i][r] * ct;
      }
      cxv += __shfl_xor(cxv, 1, 64);
      cxv += __shfl_xor(cxv, 2, 64);
      cxv += __shfl_xor(cxv, 4, 64);
      cxv += __shfl_xor(cxv, 8, 64);
      if (cL == 0) atomicAdd(&cxbuf[wr*64 + i*16 + r4 + r], cxv);
    }
  }
  if (myw) {
#pragma unroll
    for (int j = 0; j < 4; ++j) {
      py[j] += __shfl_xor(py[j], 16, 64);
      py[j] += __shfl_xor(py[j], 32, 64);
    }
    if ((lane >> 4) == 0) {
#pragma unroll
      for (int j = 0; j < 4; ++j)
        atomicAdd(&cybuf[wc*64 + j*16 + cL], py[j]);
    }
  }
  __syncthreads();
  if (t < 128) cXpart[((size_t)p*8 + yt)*NS + xt*128 + t] = cxbuf[t];
  if (myw && t < 128) cYpart[((size_t)(p-3)*8 + xt)*NS + yt*128 + t] = cybuf[t];
}

// ================= cfin: reduce cX/cY partials =================
__global__ void cfin_kernel(
    const float* __restrict__ cXpart, const float* __restrict__ cYpart,
    const float* __restrict__ sp_mxb, const float* __restrict__ pw_mxb,
    float* __restrict__ cX, float* __restrict__ cY)
{
  const int blk = blockIdx.x;
  const int p = blk >> 2;
  const int x = ((blk & 3) << 8) + threadIdx.x;
  float a = 0.f;
#pragma unroll
  for (int yt = 0; yt < 8; ++yt) a += cXpart[((size_t)p*8 + yt)*NS + x];
  cX[p*NS + x] = a + (p < 3 ? sp_mxb[p] : pw_mxb[p-3]);
  if (p >= 3) {
    float b = 0.f;
#pragma unroll
    for (int xt = 0; xt < 8; ++xt) b += cYpart[((size_t)(p-3)*8 + xt)*NS + x];
    cY[p*NS + x] = b;
  }
}

// ================= pass 2: recompute S, weighted reductions ==================
// Per yt: MFMA -> barrier -> R loads to regs (older vmem) -> issue stage(yt+1)
// (younger) -> epilogue from regs (R-waits leave stage in flight; epilogue
// covers stage latency) -> __syncthreads (drain finds stage landed).
__global__ __launch_bounds__(256, 2) void pass2_kernel(
    const unsigned short* __restrict__ emb, const unsigned short* __restrict__ Rb,
    const float* __restrict__ sp_mxw, const float* __restrict__ pw_mxw,
    const float* __restrict__ pw_myw,
    float* __restrict__ potX, float* __restrict__ potYpart)
{
  const int bid = blockIdx.x;
  const int p = bid >> 8, b = (bid >> 3) & 31, xt = bid & 7;
  const char* Ae = (const char*)(emb + (size_t)(2*p)*BSE + ((size_t)b*NS + (size_t)xt*128)*EE);
  const char* Be = (const char*)(emb + (size_t)(2*p+1)*BSE + (size_t)b*NS*EE);
  const unsigned short* Rp = Rb + (size_t)p*NS*NS;
  const float* mxw = (p < 3) ? (sp_mxw + p*NS) : (pw_mxw + (p-3)*NS);
  const float* myw = (p < 3) ? nullptr : (pw_myw + (p-3)*NS);
  __shared__ char lA[32768];
  __shared__ char lB[32768];
  __shared__ float pxbuf[128];
  __shared__ float pybuf[1024];
  const int t = threadIdx.x, lane = t & 63, wv = t >> 6;
  const int wr = wv >> 1, wc = wv & 1, cL = lane & 15, r4 = (lane >> 4) * 4, k8 = (lane >> 4) * 8;

  stage32k(Ae, lA, wv, lane);
  stage32k(Be, lB, wv, lane);
  if (t < 128) pxbuf[t] = 0.f;
#pragma unroll
  for (int k = 0; k < 4; ++k) pybuf[t + k*256] = 0.f;
  __syncthreads();

  float px[4][4];
#pragma unroll
  for (int i = 0; i < 4; ++i)
#pragma unroll
    for (int r = 0; r < 4; ++r) px[i][r] = 0.f;
  float mywv[4][4];
  if (myw) {
#pragma unroll
    for (int i = 0; i < 4; ++i)
#pragma unroll
      for (int r = 0; r < 4; ++r)
        mywv[i][r] = myw[xt*128 + wr*64 + i*16 + r4 + r];
  }

  for (int yt = 0; yt < 8; ++yt) {
    f32x4 acc[4][4];
#pragma unroll
    for (int i = 0; i < 4; ++i)
#pragma unroll
      for (int j = 0; j < 4; ++j) acc[i][j] = f32x4{0.f,0.f,0.f,0.f};
#pragma unroll
    for (int kk = 0; kk < 4; ++kk) {
      s16x8 av[4], bv[4];
#pragma unroll
      for (int i = 0; i < 4; ++i) {
        int row = wr*64 + i*16 + cL;
        av[i] = *(const s16x8*)(lA + swz(row*256 + kk*64 + k8*2));
      }
#pragma unroll
      for (int j = 0; j < 4; ++j) {
        int row = wc*64 + j*16 + cL;
        bv[j] = *(const s16x8*)(lB + swz(row*256 + kk*64 + k8*2));
      }
#pragma unroll
      for (int i = 0; i < 4; ++i)
#pragma unroll
        for (int j = 0; j < 4; ++j)
          acc[i][j] = mfma16(av[i], bv[j], acc[i][j]);
    }
    __syncthreads();   // all waves done reading lB(yt)

    // ---- R loads to registers FIRST (older than the stage below) ----
    unsigned short Rg[4][4][4];
#pragma unroll
    for (int i = 0; i < 4; ++i)
#pragma unroll
      for (int r = 0; r < 4; ++r) {
        const unsigned short* Rr = Rp + (size_t)(xt*128 + wr*64 + i*16 + r4 + r)*NS + yt*128;
#pragma unroll
        for (int j = 0; j < 4; ++j)
          Rg[i][j][r] = Rr[wc*64 + j*16 + cL];
      }
    float mxl[4];
#pragma unroll
    for (int j = 0; j < 4; ++j) mxl[j] = mxw[yt*128 + wc*64 + j*16 + cL];

    // ---- issue next-B stage (younger than R; epilogue covers its latency) ----
    if (yt < 7)
      stage32k(Be + (size_t)(yt+1)*32768, lB, wv, lane);

    // ---- epilogue from registers ----
    if (myw) {
      float py[4] = {0.f, 0.f, 0.f, 0.f};
#pragma unroll
      for (int i = 0; i < 4; ++i) {
#pragma unroll
        for (int r = 0; r < 4; ++r) {
          float pxa = 0.f;
#pragma unroll
          for (int j = 0; j < 4; ++j) {
            float tt = bf2f(Rg[i][j][r]) * acc[i][j][r];
            pxa += mxl[j] * tt;
            py[j] += mywv[i][r] * tt;
          }
          px[i][r] += pxa;
        }
      }
#pragma unroll
      for (int j = 0; j < 4; ++j) {
        py[j] += __shfl_xor(py[j], 16, 64);
        py[j] += __shfl_xor(py[j], 32, 64);
      }
      if ((lane >> 4) == 0) {
#pragma unroll
        for (int j = 0; j < 4; ++j)
          atomicAdd(&pybuf[yt*128 + wc*64 + j*16 + cL], py[j]);   // LDS atomic
      }
    } else {
#pragma unroll
      for (int i = 0; i < 4; ++i) {
#pragma unroll
        for (int r = 0; r < 4; ++r) {
          float pxa = 0.f;
#pragma unroll
          for (int j = 0; j < 4; ++j)
            pxa += mxl[j] * (bf2f(Rg[i][j][r]) * acc[i][j][r]);
          px[i][r] += pxa;
        }
      }
    }

    __syncthreads();   // stage landed (covered by epilogue) + pybuf visible
  }

#pragma unroll
  for (int msk = 1; msk < 16; msk <<= 1)
#pragma unroll
    for (int i = 0; i < 4; ++i)
#pragma unroll
      for (int r = 0; r < 4; ++r)
        px[i][r] += __shfl_xor(px[i][r], msk, 64);
  if (cL == 0) {
#pragma unroll
    for (int i = 0; i < 4; ++i)
#pragma unroll
      for (int r = 0; r < 4; ++r)
        atomicAdd(&pxbuf[wr*64 + i*16 + r4 + r], px[i][r]);
  }
  __syncthreads();
  if (t < 128) potX[((size_t)p*NB + b)*NS + (size_t)xt*128 + t] = pxbuf[t];

  if (myw) {
    const size_t base = ((size_t)((p-3)*NB + b) * 8 + xt) * NS;
#pragma unroll
    for (int k = 0; k < 4; ++k)
      potYpart[base + t + k*256] = pybuf[t + k*256];
  }
}

// ================= final A: red -> softmax -> normalized weights =============
__global__ __launch_bounds__(256, 4) void softmax_kernel(
    const float* __restrict__ unp,
    const float* __restrict__ potX, const float* __restrict__ pyp,
    const float* __restrict__ cX, const float* __restrict__ cY,
    const float* __restrict__ pw_myb, const float* __restrict__ red_w,
    float* __restrict__ wtsn)
{
  const int u = blockIdx.x >> 5, b = blockIdx.x & 31, t = threadIdx.x;
  const int lane = t & 63, wv = t >> 6;
  __shared__ float redA[4], redB[4];
  const float* unpp  = unp  + ((size_t)u*NB + b)*NS;
  const float* selfX = potX + ((size_t)u*NB + b)*NS;
  const float* cXu   = cX + u*NS;
  const float rw0 = red_w[u*4+0], rw1 = red_w[u*4+1], rw2 = red_w[u*4+2], rw3 = red_w[u*4+3];

  int ty2, ty3; const float *x2 = nullptr, *x3 = nullptr, *c2, *c3;
  const float *y2 = nullptr, *y3 = nullptr; float a2 = 0.f, a3 = 0.f;
  if (u == 0) {
    ty2 = 0; x2 = potX + ((size_t)3*NB + b)*NS; c2 = cX + 3*NS;
    ty3 = 0; x3 = potX + ((size_t)4*NB + b)*NS; c3 = cX + 4*NS;
  } else if (u == 1) {
    ty2 = 1; y2 = pyp + ((size_t)(0*NB + b) * 8) * NS; c2 = cY + 3*NS; a2 = pw_myb[0];
    ty3 = 0; x3 = potX + ((size_t)5*NB + b)*NS; c3 = cX + 5*NS;
  } else {
    ty2 = 1; y2 = pyp + ((size_t)(1*NB + b) * 8) * NS; c2 = cY + 4*NS; a2 = pw_myb[1];
    ty3 = 1; y3 = pyp + ((size_t)(2*NB + b) * 8) * NS; c3 = cY + 5*NS; a3 = pw_myb[2];
  }
  float rv[4]; float lmax = -3.4e38f;
#pragma unroll
  for (int k = 0; k < 4; ++k) {
    int s = t*4 + k;
    float t2, t3;
    if (ty2 == 0) t2 = x2[s] + c2[s];
    else {
      float a = 0.f;
#pragma unroll
      for (int q = 0; q < 8; ++q) a += y2[(size_t)q*NS + s];
      t2 = a + c2[s] + a2;
    }
    if (ty3 == 0) t3 = x3[s] + c3[s];
    else {
      float a = 0.f;
#pragma unroll
      for (int q = 0; q < 8; ++q) a += y3[(size_t)q*NS + s];
      t3 = a + c3[s] + a3;
    }
    float v = rw0*unpp[s] + rw1*(selfX[s] + cXu[s]) + rw2*t2 + rw3*t3;
    rv[k] = v; lmax = fmaxf(lmax, v);
  }
#pragma unroll
  for (int msk = 1; msk < 64; msk <<= 1) lmax = fmaxf(lmax, __shfl_xor(lmax, msk, 64));
  if (lane == 0) redA[wv] = lmax;
  __syncthreads();
  const float gmax = fmaxf(fmaxf(redA[0], redA[1]), fmaxf(redA[2], redA[3]));
  float e2v[4]; float lsum = 0.f;
#pragma unroll
  for (int k = 0; k < 4; ++k) {
    e2v[k] = __expf(rv[k] - gmax);
    lsum += e2v[k];
  }
#pragma unroll
  for (int msk = 1; msk < 64; msk <<= 1) lsum += __shfl_xor(lsum, msk, 64);
  if (lane == 0) redB[wv] = lsum;
  __syncthreads();
  const float inv = 1.f / (redB[0] + redB[1] + redB[2] + redB[3]);
  float4 w4 = {e2v[0]*inv, e2v[1]*inv, e2v[2]*inv, e2v[3]*inv};
  *(float4*)(wtsn + ((size_t)u*NB + b)*NS + t*4) = w4;
}

// ================= final B: bmm partials over s-chunks =======================
__global__ __launch_bounds__(256, 8) void bmm_kernel(
    const float* __restrict__ utils, const float* __restrict__ wtsn,
    float* __restrict__ part)
{
  const int blk = blockIdx.x;          // ((u*32+b)*8)+ch
  const int ch = blk & 7, ub = blk >> 3;
  const int b = ub & 31, u = ub >> 5;
  const int t = threadIdx.x, e = t & 127, half = t >> 7;
  __shared__ float comb[128];
  const float* w  = wtsn + (size_t)ub*NS + ch*128;
  const float* up = utils + (size_t)u*BSE + ((size_t)b*NS + ch*128)*EE;
  float acc = 0.f;
  const int s0 = half * 64;
#pragma unroll 8
  for (int s = s0; s < s0 + 64; ++s)
    acc += up[(size_t)s*EE + e] * w[s];
  if (half) comb[e] = acc;
  __syncthreads();
  if (!half) part[(size_t)blk*128 + e] = acc + comb[e];
}

// ================= final C: reduce partials =================
__global__ void fred_kernel(const float* __restrict__ part, float* __restrict__ out)
{
  const int idx = blockIdx.x * 256 + threadIdx.x;   // (u*32+b)*128 + e, 12288 total
  const int e = idx & 127, ub = idx >> 7;
  float a = 0.f;
#pragma unroll
  for (int ch = 0; ch < 8; ++ch) a += part[((size_t)ub*8 + ch)*128 + e];
  out[idx] = a;
}

// ================= host launch =================
extern "C" void kernel_launch(void* const* d_in, const int* in_sizes, int n_in,
                              void* d_out, int out_size, void* d_ws, size_t ws_size,
                              hipStream_t stream)
{
  (void)in_sizes; (void)n_in; (void)out_size; (void)ws_size;
  const float* utils  = (const float*)d_in[0];
  const float* un_w1  = (const float*)d_in[1];
  const float* un_b1  = (const float*)d_in[2];
  const float* un_w2  = (const float*)d_in[3];
  const float* un_b2  = (const float*)d_in[4];
  const float* sp_wx  = (const float*)d_in[5];
  const float* sp_bx  = (const float*)d_in[6];
  const float* sp_wy  = (const float*)d_in[7];
  const float* sp_by  = (const float*)d_in[8];
  const float* sp_g   = (const float*)d_in[9];
  const float* sp_b   = (const float*)d_in[10];
  const float* sp_mxw = (const float*)d_in[11];
  const float* sp_mxb = (const float*)d_in[12];
  const float* pw_wx  = (const float*)d_in[13];
  const float* pw_bx  = (const float*)d_in[14];
  const float* pw_wy  = (const float*)d_in[15];
  const float* pw_by  = (const float*)d_in[16];
  const float* pw_g   = (const float*)d_in[17];
  const float* pw_b   = (const float*)d_in[18];
  const float* pw_mxw = (const float*)d_in[19];
  const float* pw_mxb = (const float*)d_in[20];
  const float* pw_myw = (const float*)d_in[21];
  const float* pw_myb = (const float*)d_in[22];
  const float* red_w  = (const float*)d_in[23];
  float* out = (float*)d_out;
  char* ws = (char*)d_ws;

  unsigned short* embp  = (unsigned short*)(ws + EMB_OFF);
  float* unpp           = (float*)(ws + UNP_OFF);
  unsigned short* Rbp   = (unsigned short*)(ws + RB_OFF);
  float* cXp            = (float*)(ws + CX_OFF);
  float* potXp          = (float*)(ws + POTX_OFF);
  float* pypp           = (float*)(ws + PYP_OFF);
  float* cYp            = (float*)(ws + CY_OFF);
  float* cXpartp        = (float*)(ws + CXP_OFF);
  float* cYpartp        = (float*)(ws + CYP_OFF);
  unsigned short* wbfp  = (unsigned short*)(ws + WBF_OFF);
  float* wtsp           = (float*)(ws + WTS_OFF);
  float* partp          = (float*)(ws + PART_OFF);

  wprep_kernel<<<dim3(240), dim3(256), 0, stream>>>(
      un_w1, sp_wx, sp_wy, pw_wx, pw_wy, wbfp);
  embed_kernel<<<dim3(1536), dim3(256), 0, stream>>>(
      utils, wbfp, un_b1, un_w2, un_b2, sp_bx, sp_by, pw_bx, pw_by, embp, unpp);
  pass1_kernel<<<dim3(384), dim3(256), 0, stream>>>(
      embp, sp_g, sp_b, sp_mxw, pw_g, pw_b, pw_mxw, pw_myw,
      Rbp, cXpartp, cYpartp);
  cfin_kernel<<<dim3(24), dim3(256), 0, stream>>>(
      cXpartp, cYpartp, sp_mxb, pw_mxb, cXp, cYp);
  pass2_kernel<<<dim3(1536), dim3(256), 0, stream>>>(
      embp, Rbp, sp_mxw, pw_mxw, pw_myw, potXp, pypp);
  softmax_kernel<<<dim3(96), dim3(256), 0, stream>>>(
      unpp, potXp, pypp, cXp, cYp, pw_myb, red_w, wtsp);
  bmm_kernel<<<dim3(768), dim3(256), 0, stream>>>(
      utils, wtsp, partp);
  fred_kernel<<<dim3(48), dim3(256), 0, stream>>>(partp, out);
}

// Round 12
// 259.417 us; speedup vs baseline: 1.4184x; 1.4184x over previous
//
#include <hip/hip_runtime.h>
#include <math.h>

constexpr int EE = 128;    // embedding dim
constexpr int NS = 1024;   // spatial S
constexpr int NB = 32;     // batch
constexpr size_t BSE = (size_t)NB * NS * EE;  // 4194304 elems per (b,s,e) array

typedef __attribute__((ext_vector_type(4))) float f32x4;
typedef __attribute__((ext_vector_type(8))) short s16x8;
typedef __attribute__((ext_vector_type(4))) short s16x4;
typedef __attribute__((ext_vector_type(8))) __bf16 bf16v8;

__device__ __forceinline__ f32x4 mfma16(s16x8 a, s16x8 b, f32x4 c) {
  return __builtin_amdgcn_mfma_f32_16x16x32_bf16(
      __builtin_bit_cast(bf16v8, a), __builtin_bit_cast(bf16v8, b), c, 0, 0, 0);
}

__device__ __forceinline__ unsigned short f2bf(float f) {
  unsigned u = __builtin_bit_cast(unsigned, f);
  u += 0x7FFFu + ((u >> 16) & 1u);
  return (unsigned short)(u >> 16);
}
__device__ __forceinline__ float bf2f(unsigned short h) {
  unsigned u = ((unsigned)h) << 16;
  return __builtin_bit_cast(float, u);
}

// LDS XOR swizzles (involutions). 256B-row tiles: XOR 16B-slot bits 4-6 with row&7.
// 128B-row tiles (K-half staging): XOR bits 4-6 with bits 7-9.
__device__ __forceinline__ int swz(int b)  { return b ^ (((b >> 8) & 7) << 4); }
__device__ __forceinline__ int swz7(int b) { return b ^ (((b >> 7) & 7) << 4); }

__device__ __forceinline__ void gl_lds16(const void* gptr, void* lptr) {
  auto g = (const __attribute__((address_space(1))) unsigned int*)gptr;
  auto l = (__attribute__((address_space(3))) unsigned int*)lptr;
  __builtin_amdgcn_global_load_lds(g, l, 16, 0, 0);
}

// stage one contiguous 32KB global tile (256B rows) with source-side swz().
__device__ __forceinline__ void stage32k(const char* gsrc, char* ldst, int wv, int lane) {
#pragma unroll
  for (int c = 0; c < 8; ++c) {
    int uoff = c*4096 + wv*1024;              // wave-uniform LDS dest
    gl_lds16(gsrc + swz(uoff + lane*16), ldst + uoff);
  }
}

// stage a 16KB K-half (128B LDS rows) of a 256B-row global tile; swz7 on source.
__device__ __forceinline__ void stage_half(const char* tile, char* ldst, int kh, int wv, int lane) {
#pragma unroll
  for (int c = 0; c < 4; ++c) {
    int uoff = c*4096 + wv*1024;
    int sa = swz7(uoff + lane*16);
    gl_lds16(tile + (sa >> 7)*256 + kh*128 + (sa & 127), ldst + uoff);
  }
}

// ---------------- workspace layout (bytes) ----------------
constexpr size_t EMB_OFF   = 0;                                   // 12 bf16 arrays [p][side][b*S+s][e]
constexpr size_t UNP_OFF   = EMB_OFF + 12ull * BSE * 2;           // f32 [3][B][S]
constexpr size_t RB_OFF    = UNP_OFF + 3ull * NB * NS * 4;        // bf16 [6][S][S]
constexpr size_t CX_OFF    = RB_OFF + 6ull * NS * NS * 2;         // f32 [6][S]
constexpr size_t POTX_OFF  = CX_OFF + 6ull * NS * 4;              // f32 [6][B][S]
constexpr size_t PYP_OFF   = POTX_OFF + 6ull * NB * NS * 4;       // f32 [3][B][8][S] potY partials
constexpr size_t CY_OFF    = PYP_OFF + 3ull * NB * 8 * NS * 4;    // f32 [6][S]
constexpr size_t CXP_OFF   = CY_OFF + 6ull * NS * 4;              // f32 [6][8][S] cX partials
constexpr size_t CYP_OFF   = CXP_OFF + 6ull * 8 * NS * 4;         // f32 [3][8][S] cY partials
constexpr size_t WBF_OFF   = CYP_OFF + 3ull * 8 * NS * 4;         // bf16 [15][128*128] weights
constexpr size_t WTS_OFF   = WBF_OFF + 15ull * EE * EE * 2;       // f32 [3][B][S] softmax weights
constexpr size_t PART_OFF  = WTS_OFF + 3ull * NB * NS * 4;        // f32 [3][B][8][128] bmm partials

// ================= wprep: f32 -> bf16 weight matrices (once) =================
__global__ void wprep_kernel(
    const float* __restrict__ un_w1, const float* __restrict__ sp_wx,
    const float* __restrict__ sp_wy, const float* __restrict__ pw_wx,
    const float* __restrict__ pw_wy, unsigned short* __restrict__ wbf)
{
  const int i = (blockIdx.x * 256 + threadIdx.x) * 4;   // elem index, 245760 total
  const int m15 = i >> 14, off = i & 16383;
  const float* src;
  if (m15 < 3)       src = un_w1 + (size_t)m15 * 16384;
  else if (m15 < 6)  src = sp_wx + (size_t)(m15 - 3) * 16384;
  else if (m15 < 9)  src = sp_wy + (size_t)(m15 - 6) * 16384;
  else if (m15 < 12) src = pw_wx + (size_t)(m15 - 9) * 16384;
  else               src = pw_wy + (size_t)(m15 - 12) * 16384;
  float4 v = *(const float4*)(src + off);
  s16x4 h;
  h.x = (short)f2bf(v.x); h.y = (short)f2bf(v.y);
  h.z = (short)f2bf(v.z); h.w = (short)f2bf(v.w);
  *(s16x4*)(wbf + i) = h;
}

// ================= embed kernel (fused; bf16 weights staged async) ===========
__global__ __launch_bounds__(256, 3) void embed_kernel(
    const float* __restrict__ utils, const unsigned short* __restrict__ wbf,
    const float* __restrict__ un_b1, const float* __restrict__ un_w2,
    const float* __restrict__ un_b2,
    const float* __restrict__ sp_bx, const float* __restrict__ sp_by,
    const float* __restrict__ pw_bx, const float* __restrict__ pw_by,
    unsigned short* __restrict__ emb, float* __restrict__ unp)
{
  const int u  = blockIdx.x >> 9;
  const int pt = blockIdx.x & 511;

  __shared__ short lA[64*128];
  __shared__ short lB[128*128];
  __shared__ float redbuf[64];

  const int t = threadIdx.x;
  {
    const char* src = (const char*)(utils + (size_t)u*BSE + (size_t)pt*64*EE);
#pragma unroll
    for (int c = 0; c < 8; ++c) {
      int off = c*4096 + t*16;
      float4 v = *(const float4*)(src + off);
      s16x4 h;
      h.x = (short)f2bf(v.x); h.y = (short)f2bf(v.y);
      h.z = (short)f2bf(v.z); h.w = (short)f2bf(v.w);
      *(s16x4*)((char*)lA + swz(off >> 1)) = h;
    }
  }

  const int lane = t & 63, wv = t >> 6;
  const int wrE = wv & 1, wcE = wv >> 1;
  const int cL = lane & 15, r4 = (lane >> 4) * 4, k8 = (lane >> 4) * 8;

  for (int m = 0; m < 5; ++m) {
    int wid; const float* bias;
    unsigned short* dst = nullptr;
    int mode;
    if (m == 0)      { wid = u;     bias = un_b1 + u*EE; mode = 0; }
    else if (m == 1) { wid = 3 + u; bias = sp_bx + u*EE; dst = emb + (size_t)(2*u)*BSE;   mode = 1; }
    else if (m == 2) { wid = 6 + u; bias = sp_by + u*EE; dst = emb + (size_t)(2*u+1)*BSE; mode = 1; }
    else {
      int q, side;
      if (u == 0)      { q = (m == 3) ? 0 : 1; side = 0; }
      else if (u == 1) { if (m == 3) { q = 0; side = 1; } else { q = 2; side = 0; } }
      else             { q = (m == 3) ? 1 : 2; side = 1; }
      wid  = (side == 0 ? 9 : 12) + q;
      bias = (side == 0 ? pw_bx : pw_by) + q*EE;
      dst  = emb + (size_t)(2*(3+q)+side)*BSE;
      mode = 1;
    }

    __syncthreads();   // lA writes done (m=0) / prev iter's lB reads done
    stage32k((const char*)wbf + (size_t)wid * 32768, (char*)lB, wv, lane);
    __syncthreads();   // drain: lB ready

    f32x4 acc[2][4];
#pragma unroll
    for (int i = 0; i < 2; ++i)
#pragma unroll
      for (int j = 0; j < 4; ++j) acc[i][j] = f32x4{0.f, 0.f, 0.f, 0.f};

#pragma unroll
    for (int kk = 0; kk < 4; ++kk) {
      s16x8 av[2], bv[4];
#pragma unroll
      for (int i = 0; i < 2; ++i) {
        int row = wrE*32 + i*16 + cL;
        av[i] = *(const s16x8*)((const char*)lA + swz(row*256 + kk*64 + k8*2));
      }
#pragma unroll
      for (int j = 0; j < 4; ++j) {
        int row = wcE*64 + j*16 + cL;
        bv[j] = *(const s16x8*)((const char*)lB + swz(row*256 + kk*64 + k8*2));
      }
#pragma unroll
      for (int i = 0; i < 2; ++i)
#pragma unroll
        for (int j = 0; j < 4; ++j)
          acc[i][j] = mfma16(av[i], bv[j], acc[i][j]);
    }

    if (mode == 0) {
      const float* w2 = un_w2 + u*EE;
      float s[2][4];
#pragma unroll
      for (int i = 0; i < 2; ++i)
#pragma unroll
        for (int r = 0; r < 4; ++r) s[i][r] = 0.f;
#pragma unroll
      for (int i = 0; i < 2; ++i) {
#pragma unroll
        for (int j = 0; j < 4; ++j) {
          int o = wcE*64 + j*16 + cL;
          float bv2 = bias[o], w2v = w2[o];
#pragma unroll
          for (int r = 0; r < 4; ++r) {
            float v = acc[i][j][r] + bv2;
            v = v > 0.f ? v : 0.f;
            s[i][r] += v * w2v;
          }
        }
      }
#pragma unroll
      for (int msk = 1; msk < 16; msk <<= 1)
#pragma unroll
        for (int i = 0; i < 2; ++i)
#pragma unroll
          for (int r = 0; r < 4; ++r)
            s[i][r] += __shfl_xor(s[i][r], msk, 64);
      if (t < 64) redbuf[t] = 0.f;
      __syncthreads();
      if (cL == 0) {
#pragma unroll
        for (int i = 0; i < 2; ++i)
#pragma unroll
          for (int r = 0; r < 4; ++r)
            atomicAdd(&redbuf[wrE*32 + i*16 + r4 + r], s[i][r]);
      }
      __syncthreads();
      if (t < 64) unp[(size_t)u*NB*NS + (size_t)pt*64 + t] = redbuf[t] + un_b2[u];
    } else {
      float nrm[2][4];
#pragma unroll
      for (int i = 0; i < 2; ++i)
#pragma unroll
        for (int r = 0; r < 4; ++r) nrm[i][r] = 0.f;
#pragma unroll
      for (int i = 0; i < 2; ++i) {
#pragma unroll
        for (int j = 0; j < 4; ++j) {
          int o = wcE*64 + j*16 + cL;
          float bv2 = bias[o];
#pragma unroll
          for (int r = 0; r < 4; ++r) {
            acc[i][j][r] += bv2;
            nrm[i][r] += acc[i][j][r] * acc[i][j][r];
          }
        }
      }
#pragma unroll
      for (int msk = 1; msk < 16; msk <<= 1)
#pragma unroll
        for (int i = 0; i < 2; ++i)
#pragma unroll
          for (int r = 0; r < 4; ++r)
            nrm[i][r] += __shfl_xor(nrm[i][r], msk, 64);
      if (t < 64) redbuf[t] = 0.f;
      __syncthreads();
      if (cL == 0) {
#pragma unroll
        for (int i = 0; i < 2; ++i)
#pragma unroll
          for (int r = 0; r < 4; ++r)
            atomicAdd(&redbuf[wrE*32 + i*16 + r4 + r], nrm[i][r]);
      }
      __syncthreads();
#pragma unroll
      for (int i = 0; i < 2; ++i) {
#pragma unroll
        for (int r = 0; r < 4; ++r) {
          float n = redbuf[wrE*32 + i*16 + r4 + r];
          float sc = 1.f / fmaxf(sqrtf(n), 1e-12f);
          size_t pbase = ((size_t)pt*64 + wrE*32 + i*16 + r4 + r) * EE;
#pragma unroll
          for (int j = 0; j < 4; ++j) {
            int o = wcE*64 + j*16 + cL;
            dst[pbase + o] = f2bf(acc[i][j][r] * sc);
          }
        }
      }
    }
  }
}

// ================= pass 1: batch stats of S, fused BN-stats epilogue =========
// r10-proven: 64 K-half async-dbuf steps with __syncthreads pipeline.
__global__ __launch_bounds__(256, 2) void pass1_kernel(
    const unsigned short* __restrict__ emb,
    const float* __restrict__ sp_g, const float* __restrict__ sp_b,
    const float* __restrict__ sp_mxw,
    const float* __restrict__ pw_g, const float* __restrict__ pw_b,
    const float* __restrict__ pw_mxw, const float* __restrict__ pw_myw,
    unsigned short* __restrict__ Rb, float* __restrict__ cXpart,
    float* __restrict__ cYpart)
{
  const int bid = blockIdx.x;
  const int p = bid >> 6, xt = (bid >> 3) & 7, yt = bid & 7;
  const char* Xe = (const char*)(emb + (size_t)(2*p)*BSE + (size_t)xt*128*EE);
  const char* Ye = (const char*)(emb + (size_t)(2*p+1)*BSE + (size_t)yt*128*EE);
  __shared__ char lds[65536];   // buf[2] x (A-half 16K | B-half 16K)
  __shared__ float cxbuf[128];
  __shared__ float cybuf[128];
  const int t = threadIdx.x, lane = t & 63, wv = t >> 6;
  const int wr = wv >> 1, wc = wv & 1, cL = lane & 15, r4 = (lane >> 4) * 4;
  const int q16 = (lane >> 4) * 16;   // byte offset of K-subslice in 128B row

  f32x4 sS[4][4], sQ[4][4], acc[4][4];
#pragma unroll
  for (int i = 0; i < 4; ++i)
#pragma unroll
    for (int j = 0; j < 4; ++j) { sS[i][j] = f32x4{0.f,0.f,0.f,0.f}; sQ[i][j] = f32x4{0.f,0.f,0.f,0.f}; }

  stage_half(Xe, lds, 0, wv, lane);
  stage_half(Ye, lds + 16384, 0, wv, lane);
  if (t < 128) { cxbuf[t] = 0.f; cybuf[t] = 0.f; }
  __syncthreads();

  for (int s = 0; s < 2*NB; ++s) {
    const int cur = s & 1;
    const char* buf = lds + cur * 32768;
    if (s + 1 < 2*NB) {
      const int b1 = (s + 1) >> 1, kh1 = (s + 1) & 1;
      char* nb = lds + (cur ^ 1) * 32768;
      stage_half(Xe + (size_t)b1*NS*EE*2, nb, kh1, wv, lane);
      stage_half(Ye + (size_t)b1*NS*EE*2, nb + 16384, kh1, wv, lane);
    }
    if ((s & 1) == 0) {
#pragma unroll
      for (int i = 0; i < 4; ++i)
#pragma unroll
        for (int j = 0; j < 4; ++j) acc[i][j] = f32x4{0.f,0.f,0.f,0.f};
    }
#pragma unroll
    for (int kk2 = 0; kk2 < 2; ++kk2) {
      s16x8 av[4], bv[4];
#pragma unroll
      for (int i = 0; i < 4; ++i) {
        int row = wr*64 + i*16 + cL;
        av[i] = *(const s16x8*)(buf + swz7(row*128 + kk2*64 + q16));
      }
#pragma unroll
      for (int j = 0; j < 4; ++j) {
        int row = wc*64 + j*16 + cL;
        bv[j] = *(const s16x8*)(buf + 16384 + swz7(row*128 + kk2*64 + q16));
      }
#pragma unroll
      for (int i = 0; i < 4; ++i)
#pragma unroll
        for (int j = 0; j < 4; ++j)
          acc[i][j] = mfma16(av[i], bv[j], acc[i][j]);
    }
    if (s & 1) {
#pragma unroll
      for (int i = 0; i < 4; ++i)
#pragma unroll
        for (int j = 0; j < 4; ++j) {
          sS[i][j] += acc[i][j];
          sQ[i][j] += acc[i][j] * acc[i][j];
        }
    }
    __syncthreads();
  }

  // ---- fused BN-stats epilogue ----
  const float* gp  = (p < 3) ? (sp_g + (size_t)p*NS*NS) : (pw_g + (size_t)(p-3)*NS*NS);
  const float* bbp = (p < 3) ? (sp_b + (size_t)p*NS*NS) : (pw_b + (size_t)(p-3)*NS*NS);
  const float* mxw = (p < 3) ? (sp_mxw + p*NS) : (pw_mxw + (p-3)*NS);
  const float* myw = (p < 3) ? nullptr : (pw_myw + (p-3)*NS);
  unsigned short* Rp = Rb + (size_t)p*NS*NS;
  const float inv = 1.f / 32.f;

  float mxl[4];
#pragma unroll
  for (int j = 0; j < 4; ++j) mxl[j] = mxw[yt*128 + wc*64 + j*16 + cL];
  float mywr[4][4];
  if (myw) {
#pragma unroll
    for (int i = 0; i < 4; ++i)
#pragma unroll
      for (int r = 0; r < 4; ++r)
        mywr[i][r] = myw[xt*128 + wr*64 + i*16 + r4 + r];
  }

  float py[4] = {0.f, 0.f, 0.f, 0.f};
#pragma unroll
  for (int i = 0; i < 4; ++i) {
#pragma unroll
    for (int r = 0; r < 4; ++r) {
      const size_t rowoff = (size_t)(xt*128 + wr*64 + i*16 + r4 + r)*NS + yt*128;
      float cxv = 0.f;
#pragma unroll
      for (int j = 0; j < 4; ++j) {
        int c = wc*64 + j*16 + cL;
        float mean = sS[i][j][r] * inv;
        float var  = sQ[i][j][r] * inv - mean * mean;
        float rstd = rsqrtf(var + 1e-5f);
        unsigned short rh = f2bf(gp[rowoff + c] * rstd);
        Rp[rowoff + c] = rh;
        float ct = bbp[rowoff + c] - bf2f(rh) * mean;
        cxv += mxl[j] * ct;
        if (myw) py[j] += mywr[i][r] * ct;
      }
      cxv += __shfl_xor(cxv, 1, 64);
      cxv += __shfl_xor(cxv, 2, 64);
      cxv += __shfl_xor(cxv, 4, 64);
      cxv += __shfl_xor(cxv, 8, 64);
      if (cL == 0) atomicAdd(&cxbuf[wr*64 + i*16 + r4 + r], cxv);
    }
  }
  if (myw) {
#pragma unroll
    for (int j = 0; j < 4; ++j) {
      py[j] += __shfl_xor(py[j], 16, 64);
      py[j] += __shfl_xor(py[j], 32, 64);
    }
    if ((lane >> 4) == 0) {
#pragma unroll
      for (int j = 0; j < 4; ++j)
        atomicAdd(&cybuf[wc*64 + j*16 + cL], py[j]);
    }
  }
  __syncthreads();
  if (t < 128) cXpart[((size_t)p*8 + yt)*NS + xt*128 + t] = cxbuf[t];
  if (myw && t < 128) cYpart[((size_t)(p-3)*8 + xt)*NS + yt*128 + t] = cybuf[t];
}

// ================= cfin: reduce cX/cY partials =================
__global__ void cfin_kernel(
    const float* __restrict__ cXpart, const float* __restrict__ cYpart,
    const float* __restrict__ sp_mxb, const float* __restrict__ pw_mxb,
    float* __restrict__ cX, float* __restrict__ cY)
{
  const int blk = blockIdx.x;
  const int p = blk >> 2;
  const int x = ((blk & 3) << 8) + threadIdx.x;
  float a = 0.f;
#pragma unroll
  for (int yt = 0; yt < 8; ++yt) a += cXpart[((size_t)p*8 + yt)*NS + x];
  cX[p*NS + x] = a + (p < 3 ? sp_mxb[p] : pw_mxb[p-3]);
  if (p >= 3) {
    float b = 0.f;
#pragma unroll
    for (int xt = 0; xt < 8; ++xt) b += cYpart[((size_t)(p-3)*8 + xt)*NS + x];
    cY[p*NS + x] = b;
  }
}

// ================= pass 2: recompute S, weighted reductions (r10-proven) =====
// A in LDS, B single-buffered, inline interleaved R loads (VGPR-light),
// LDS pybuf accumulation, exclusive partial writes. Do NOT hoist R to regs
// (r7/r11 both regressed 2-3x: load-burst + VGPR cliff).
__global__ __launch_bounds__(256, 2) void pass2_kernel(
    const unsigned short* __restrict__ emb, const unsigned short* __restrict__ Rb,
    const float* __restrict__ sp_mxw, const float* __restrict__ pw_mxw,
    const float* __restrict__ pw_myw,
    float* __restrict__ potX, float* __restrict__ potYpart)
{
  const int bid = blockIdx.x;
  const int p = bid >> 8, b = (bid >> 3) & 31, xt = bid & 7;
  const char* Ae = (const char*)(emb + (size_t)(2*p)*BSE + ((size_t)b*NS + (size_t)xt*128)*EE);
  const char* Be = (const char*)(emb + (size_t)(2*p+1)*BSE + (size_t)b*NS*EE);
  const unsigned short* Rp = Rb + (size_t)p*NS*NS;
  const float* mxw = (p < 3) ? (sp_mxw + p*NS) : (pw_mxw + (p-3)*NS);
  const float* myw = (p < 3) ? nullptr : (pw_myw + (p-3)*NS);
  __shared__ char lA[32768];
  __shared__ char lB[32768];
  __shared__ float pxbuf[128];
  __shared__ float pybuf[1024];
  const int t = threadIdx.x, lane = t & 63, wv = t >> 6;
  const int wr = wv >> 1, wc = wv & 1, cL = lane & 15, r4 = (lane >> 4) * 4, k8 = (lane >> 4) * 8;

  stage32k(Ae, lA, wv, lane);
  stage32k(Be, lB, wv, lane);
  if (t < 128) pxbuf[t] = 0.f;
#pragma unroll
  for (int k = 0; k < 4; ++k) pybuf[t + k*256] = 0.f;
  __syncthreads();

  float px[4][4];
#pragma unroll
  for (int i = 0; i < 4; ++i)
#pragma unroll
    for (int r = 0; r < 4; ++r) px[i][r] = 0.f;
  float mywv[4][4];
  if (myw) {
#pragma unroll
    for (int i = 0; i < 4; ++i)
#pragma unroll
      for (int r = 0; r < 4; ++r)
        mywv[i][r] = myw[xt*128 + wr*64 + i*16 + r4 + r];
  }

  for (int yt = 0; yt < 8; ++yt) {
    f32x4 acc[4][4];
#pragma unroll
    for (int i = 0; i < 4; ++i)
#pragma unroll
      for (int j = 0; j < 4; ++j) acc[i][j] = f32x4{0.f,0.f,0.f,0.f};
#pragma unroll
    for (int kk = 0; kk < 4; ++kk) {
      s16x8 av[4], bv[4];
#pragma unroll
      for (int i = 0; i < 4; ++i) {
        int row = wr*64 + i*16 + cL;
        av[i] = *(const s16x8*)(lA + swz(row*256 + kk*64 + k8*2));
      }
#pragma unroll
      for (int j = 0; j < 4; ++j) {
        int row = wc*64 + j*16 + cL;
        bv[j] = *(const s16x8*)(lB + swz(row*256 + kk*64 + k8*2));
      }
#pragma unroll
      for (int i = 0; i < 4; ++i)
#pragma unroll
        for (int j = 0; j < 4; ++j)
          acc[i][j] = mfma16(av[i], bv[j], acc[i][j]);
    }
    __syncthreads();   // all waves done reading lB(yt)

    float mxl[4];
#pragma unroll
    for (int j = 0; j < 4; ++j) mxl[j] = mxw[yt*128 + wc*64 + j*16 + cL];

    if (myw) {
      float py[4] = {0.f, 0.f, 0.f, 0.f};
#pragma unroll
      for (int i = 0; i < 4; ++i) {
#pragma unroll
        for (int r = 0; r < 4; ++r) {
          const unsigned short* Rr = Rp + (size_t)(xt*128 + wr*64 + i*16 + r4 + r)*NS + yt*128;
          float pxa = 0.f;
#pragma unroll
          for (int j = 0; j < 4; ++j) {
            float Rv = bf2f(Rr[wc*64 + j*16 + cL]);
            float tt = Rv * acc[i][j][r];
            pxa += mxl[j] * tt;
            py[j] += mywv[i][r] * tt;
          }
          px[i][r] += pxa;
        }
      }
#pragma unroll
      for (int j = 0; j < 4; ++j) {
        py[j] += __shfl_xor(py[j], 16, 64);
        py[j] += __shfl_xor(py[j], 32, 64);
      }
      if ((lane >> 4) == 0) {
#pragma unroll
        for (int j = 0; j < 4; ++j)
          atomicAdd(&pybuf[yt*128 + wc*64 + j*16 + cL], py[j]);   // LDS atomic
      }
    } else {
#pragma unroll
      for (int i = 0; i < 4; ++i) {
#pragma unroll
        for (int r = 0; r < 4; ++r) {
          const unsigned short* Rr = Rp + (size_t)(xt*128 + wr*64 + i*16 + r4 + r)*NS + yt*128;
          float pxa = 0.f;
#pragma unroll
          for (int j = 0; j < 4; ++j) {
            float Rv = bf2f(Rr[wc*64 + j*16 + cL]);
            pxa += mxl[j] * (Rv * acc[i][j][r]);
          }
          px[i][r] += pxa;
        }
      }
    }

    if (yt < 7)
      stage32k(Be + (size_t)(yt+1)*32768, lB, wv, lane);
    __syncthreads();   // stage landed + pybuf adds visible
  }

#pragma unroll
  for (int msk = 1; msk < 16; msk <<= 1)
#pragma unroll
    for (int i = 0; i < 4; ++i)
#pragma unroll
      for (int r = 0; r < 4; ++r)
        px[i][r] += __shfl_xor(px[i][r], msk, 64);
  if (cL == 0) {
#pragma unroll
    for (int i = 0; i < 4; ++i)
#pragma unroll
      for (int r = 0; r < 4; ++r)
        atomicAdd(&pxbuf[wr*64 + i*16 + r4 + r], px[i][r]);
  }
  __syncthreads();
  if (t < 128) potX[((size_t)p*NB + b)*NS + (size_t)xt*128 + t] = pxbuf[t];

  if (myw) {
    const size_t base = ((size_t)((p-3)*NB + b) * 8 + xt) * NS;
#pragma unroll
    for (int k = 0; k < 4; ++k)
      potYpart[base + t + k*256] = pybuf[t + k*256];
  }
}

// ================= final A: red -> softmax -> normalized weights =============
__global__ __launch_bounds__(256, 4) void softmax_kernel(
    const float* __restrict__ unp,
    const float* __restrict__ potX, const float* __restrict__ pyp,
    const float* __restrict__ cX, const float* __restrict__ cY,
    const float* __restrict__ pw_myb, const float* __restrict__ red_w,
    float* __restrict__ wtsn)
{
  const int u = blockIdx.x >> 5, b = blockIdx.x & 31, t = threadIdx.x;
  const int lane = t & 63, wv = t >> 6;
  __shared__ float redA[4], redB[4];
  const float* unpp  = unp  + ((size_t)u*NB + b)*NS;
  const float* selfX = potX + ((size_t)u*NB + b)*NS;
  const float* cXu   = cX + u*NS;
  const float rw0 = red_w[u*4+0], rw1 = red_w[u*4+1], rw2 = red_w[u*4+2], rw3 = red_w[u*4+3];

  int ty2, ty3; const float *x2 = nullptr, *x3 = nullptr, *c2, *c3;
  const float *y2 = nullptr, *y3 = nullptr; float a2 = 0.f, a3 = 0.f;
  if (u == 0) {
    ty2 = 0; x2 = potX + ((size_t)3*NB + b)*NS; c2 = cX + 3*NS;
    ty3 = 0; x3 = potX + ((size_t)4*NB + b)*NS; c3 = cX + 4*NS;
  } else if (u == 1) {
    ty2 = 1; y2 = pyp + ((size_t)(0*NB + b) * 8) * NS; c2 = cY + 3*NS; a2 = pw_myb[0];
    ty3 = 0; x3 = potX + ((size_t)5*NB + b)*NS; c3 = cX + 5*NS;
  } else {
    ty2 = 1; y2 = pyp + ((size_t)(1*NB + b) * 8) * NS; c2 = cY + 4*NS; a2 = pw_myb[1];
    ty3 = 1; y3 = pyp + ((size_t)(2*NB + b) * 8) * NS; c3 = cY + 5*NS; a3 = pw_myb[2];
  }
  float rv[4]; float lmax = -3.4e38f;
#pragma unroll
  for (int k = 0; k < 4; ++k) {
    int s = t*4 + k;
    float t2, t3;
    if (ty2 == 0) t2 = x2[s] + c2[s];
    else {
      float a = 0.f;
#pragma unroll
      for (int q = 0; q < 8; ++q) a += y2[(size_t)q*NS + s];
      t2 = a + c2[s] + a2;
    }
    if (ty3 == 0) t3 = x3[s] + c3[s];
    else {
      float a = 0.f;
#pragma unroll
      for (int q = 0; q < 8; ++q) a += y3[(size_t)q*NS + s];
      t3 = a + c3[s] + a3;
    }
    float v = rw0*unpp[s] + rw1*(selfX[s] + cXu[s]) + rw2*t2 + rw3*t3;
    rv[k] = v; lmax = fmaxf(lmax, v);
  }
#pragma unroll
  for (int msk = 1; msk < 64; msk <<= 1) lmax = fmaxf(lmax, __shfl_xor(lmax, msk, 64));
  if (lane == 0) redA[wv] = lmax;
  __syncthreads();
  const float gmax = fmaxf(fmaxf(redA[0], redA[1]), fmaxf(redA[2], redA[3]));
  float e2v[4]; float lsum = 0.f;
#pragma unroll
  for (int k = 0; k < 4; ++k) {
    e2v[k] = __expf(rv[k] - gmax);
    lsum += e2v[k];
  }
#pragma unroll
  for (int msk = 1; msk < 64; msk <<= 1) lsum += __shfl_xor(lsum, msk, 64);
  if (lane == 0) redB[wv] = lsum;
  __syncthreads();
  const float inv = 1.f / (redB[0] + redB[1] + redB[2] + redB[3]);
  float4 w4 = {e2v[0]*inv, e2v[1]*inv, e2v[2]*inv, e2v[3]*inv};
  *(float4*)(wtsn + ((size_t)u*NB + b)*NS + t*4) = w4;
}

// ================= final B: bmm partials over s-chunks =======================
__global__ __launch_bounds__(256, 8) void bmm_kernel(
    const float* __restrict__ utils, const float* __restrict__ wtsn,
    float* __restrict__ part)
{
  const int blk = blockIdx.x;          // ((u*32+b)*8)+ch
  const int ch = blk & 7, ub = blk >> 3;
  const int b = ub & 31, u = ub >> 5;
  const int t = threadIdx.x, e = t & 127, half = t >> 7;
  __shared__ float comb[128];
  const float* w  = wtsn + (size_t)ub*NS + ch*128;
  const float* up = utils + (size_t)u*BSE + ((size_t)b*NS + ch*128)*EE;
  float acc = 0.f;
  const int s0 = half * 64;
#pragma unroll 8
  for (int s = s0; s < s0 + 64; ++s)
    acc += up[(size_t)s*EE + e] * w[s];
  if (half) comb[e] = acc;
  __syncthreads();
  if (!half) part[(size_t)blk*128 + e] = acc + comb[e];
}

// ================= final C: reduce partials =================
__global__ void fred_kernel(const float* __restrict__ part, float* __restrict__ out)
{
  const int idx = blockIdx.x * 256 + threadIdx.x;   // (u*32+b)*128 + e, 12288 total
  const int e = idx & 127, ub = idx >> 7;
  float a = 0.f;
#pragma unroll
  for (int ch = 0; ch < 8; ++ch) a += part[((size_t)ub*8 + ch)*128 + e];
  out[idx] = a;
}

// ================= host launch =================
extern "C" void kernel_launch(void* const* d_in, const int* in_sizes, int n_in,
                              void* d_out, int out_size, void* d_ws, size_t ws_size,
                              hipStream_t stream)
{
  (void)in_sizes; (void)n_in; (void)out_size; (void)ws_size;
  const float* utils  = (const float*)d_in[0];
  const float* un_w1  = (const float*)d_in[1];
  const float* un_b1  = (const float*)d_in[2];
  const float* un_w2  = (const float*)d_in[3];
  const float* un_b2  = (const float*)d_in[4];
  const float* sp_wx  = (const float*)d_in[5];
  const float* sp_bx  = (const float*)d_in[6];
  const float* sp_wy  = (const float*)d_in[7];
  const float* sp_by  = (const float*)d_in[8];
  const float* sp_g   = (const float*)d_in[9];
  const float* sp_b   = (const float*)d_in[10];
  const float* sp_mxw = (const float*)d_in[11];
  const float* sp_mxb = (const float*)d_in[12];
  const float* pw_wx  = (const float*)d_in[13];
  const float* pw_bx  = (const float*)d_in[14];
  const float* pw_wy  = (const float*)d_in[15];
  const float* pw_by  = (const float*)d_in[16];
  const float* pw_g   = (const float*)d_in[17];
  const float* pw_b   = (const float*)d_in[18];
  const float* pw_mxw = (const float*)d_in[19];
  const float* pw_mxb = (const float*)d_in[20];
  const float* pw_myw = (const float*)d_in[21];
  const float* pw_myb = (const float*)d_in[22];
  const float* red_w  = (const float*)d_in[23];
  float* out = (float*)d_out;
  char* ws = (char*)d_ws;

  unsigned short* embp  = (unsigned short*)(ws + EMB_OFF);
  float* unpp           = (float*)(ws + UNP_OFF);
  unsigned short* Rbp   = (unsigned short*)(ws + RB_OFF);
  float* cXp            = (float*)(ws + CX_OFF);
  float* potXp          = (float*)(ws + POTX_OFF);
  float* pypp           = (float*)(ws + PYP_OFF);
  float* cYp            = (float*)(ws + CY_OFF);
  float* cXpartp        = (float*)(ws + CXP_OFF);
  float* cYpartp        = (float*)(ws + CYP_OFF);
  unsigned short* wbfp  = (unsigned short*)(ws + WBF_OFF);
  float* wtsp           = (float*)(ws + WTS_OFF);
  float* partp          = (float*)(ws + PART_OFF);

  wprep_kernel<<<dim3(240), dim3(256), 0, stream>>>(
      un_w1, sp_wx, sp_wy, pw_wx, pw_wy, wbfp);
  embed_kernel<<<dim3(1536), dim3(256), 0, stream>>>(
      utils, wbfp, un_b1, un_w2, un_b2, sp_bx, sp_by, pw_bx, pw_by, embp, unpp);
  pass1_kernel<<<dim3(384), dim3(256), 0, stream>>>(
      embp, sp_g, sp_b, sp_mxw, pw_g, pw_b, pw_mxw, pw_myw,
      Rbp, cXpartp, cYpartp);
  cfin_kernel<<<dim3(24), dim3(256), 0, stream>>>(
      cXpartp, cYpartp, sp_mxb, pw_mxb, cXp, cYp);
  pass2_kernel<<<dim3(1536), dim3(256), 0, stream>>>(
      embp, Rbp, sp_mxw, pw_mxw, pw_myw, potXp, pypp);
  softmax_kernel<<<dim3(96), dim3(256), 0, stream>>>(
      unpp, potXp, pypp, cXp, cYp, pw_myb, red_w, wtsp);
  bmm_kernel<<<dim3(768), dim3(256), 0, stream>>>(
      utils, wtsp, partp);
  fred_kernel<<<dim3(48), dim3(256), 0, stream>>>(partp, out);
}